// Round 3
// baseline (194.238 us; speedup 1.0000x reference)
//
#include <hip/hip_runtime.h>
#include <hip/hip_fp16.h>
#include <math.h>

// ---------------------------------------------------------------------------
// A3TGCN2 collapsed (H0 == 0 in every cell):
//   out[n,o] = sum_t p[t] * (1 - sigmoid(pre_z[n,t,o])) * tanh(pre_h[n,t,o])
//   pre_g[n,t,o] = sum_f Agg(X)[n,f,t] * Mg[o,f] + cg[o]
//   Mg = Lg[:, :O] @ Wg (32x32), cg = Lg[:, :O] @ bg + lg_b
//   Agg = sym-normalized adjacency (+self loops) applied ONCE to raw X rows.
// R3: fused convert|count|prep kernel, memset for init, v_fma_mix inner loop,
//     32-bit saddr addressing, 4-node/256-thread k_main blocks, unroll 8.
// ---------------------------------------------------------------------------

// one u64 atomic per edge: high 32 = weight sum in 2^-24 fixed point, low = count
__global__ __launch_bounds__(256) void k_fused(
    const float* __restrict__ X, const int* __restrict__ ei,
    const float* __restrict__ ew, unsigned long long* __restrict__ pk,
    __half* __restrict__ Xh,
    const float* __restrict__ Wz, const float* __restrict__ bz,
    const float* __restrict__ Wh, const float* __restrict__ bh,
    const float* __restrict__ Lz, const float* __restrict__ lzb,
    const float* __restrict__ Lh, const float* __restrict__ lhb,
    const float* __restrict__ att,
    float* __restrict__ Mt, float* __restrict__ cvec, float* __restrict__ p,
    int E, long n8, int nbe) {
  int b = blockIdx.x;
  int tid = threadIdx.x;
  if (b < 2) {                      // ---- prep (2 blocks) ----
    int g = b;
    const float* L  = g ? Lh  : Lz;
    const float* W  = g ? Wh  : Wz;
    const float* bb = g ? bh  : bz;
    const float* lb = g ? lhb : lzb;
    int o = tid & 31;
    for (int f = tid >> 5; f < 32; f += 8) {
      float s = 0.f;
      for (int k = 0; k < 32; ++k) s += L[o * 64 + k] * W[k * 32 + f];
      Mt[g * 1024 + f * 32 + o] = s;      // transposed [g][f][o]
    }
    if (tid < 32) {
      float c = lb[tid];
      for (int k = 0; k < 32; ++k) c += L[tid * 64 + k] * bb[k];
      cvec[g * 32 + tid] = c;
    }
    if (g == 0 && tid == 0) {
      float m = att[0];
      for (int t = 1; t < 8; ++t) m = fmaxf(m, att[t]);
      float e8[8], sm = 0.f;
      for (int t = 0; t < 8; ++t) { e8[t] = expf(att[t] - m); sm += e8[t]; }
      for (int t = 0; t < 8; ++t) p[t] = e8[t] / sm;
    }
    return;
  }
  b -= 2;
  if (b < nbe) {                    // ---- degree count (atomic-bound) ----
    int e = b * 256 + tid;
    if (e < E) {
      int c = ei[E + e];
      unsigned wfx = (unsigned)(ew[e] * 16777216.0f + 0.5f);
      atomicAdd(pk + c, ((unsigned long long)wfx << 32) | 1ull);
    }
    return;
  }
  b -= nbe;                         // ---- X -> fp16 convert (BW-bound) ----
  long i = (long)b * 256 + tid;
  if (i < n8) {
    const float4* Xv = (const float4*)X;
    float4 a = Xv[2 * i], c = Xv[2 * i + 1];
    union { int4 i4; __half2 h[4]; } u;
    u.h[0] = __floats2half2_rn(a.x, a.y);
    u.h[1] = __floats2half2_rn(a.z, a.w);
    u.h[2] = __floats2half2_rn(c.x, c.y);
    u.h[3] = __floats2half2_rn(c.z, c.w);
    ((int4*)Xh)[i] = u.i4;
  }
}

// per-1024-node block: partial count sums + dinv
__global__ __launch_bounds__(256) void k_bsum(const unsigned long long* __restrict__ pk,
                                              float* __restrict__ dinv,
                                              int* __restrict__ bsum, int n) {
  int b = blockIdx.x, tid = threadIdx.x;
  int base = b * 1024 + tid * 4;
  int s = 0;
#pragma unroll
  for (int k = 0; k < 4; ++k) {
    int i = base + k;
    if (i < n) {
      unsigned long long v = pk[i];
      s += (int)(v & 0xffffffffull);
      float deg = (float)(v >> 32) * (1.0f / 16777216.0f) + 1.0f;  // +1 self
      dinv[i] = rsqrtf(deg);
    }
  }
  __shared__ int sm[256];
  sm[tid] = s;
  __syncthreads();
  for (int off = 128; off > 0; off >>= 1) {
    if (tid < off) sm[tid] += sm[tid + off];
    __syncthreads();
  }
  if (tid == 0) bsum[b] = sm[0];
}

__global__ __launch_bounds__(256) void k_bscan(const int* __restrict__ bsum,
                                               int* __restrict__ boff, int nb) {
  __shared__ int sm[256];
  int tid = threadIdx.x;
  sm[tid] = (tid < nb) ? bsum[tid] : 0;
  __syncthreads();
  for (int off = 1; off < 256; off <<= 1) {
    int v = (tid >= off) ? sm[tid - off] : 0;
    __syncthreads();
    sm[tid] += v;
    __syncthreads();
  }
  if (tid < nb) boff[tid] = tid ? sm[tid - 1] : 0;
}

__global__ __launch_bounds__(256) void k_offsets(const unsigned long long* __restrict__ pk,
                                                 const int* __restrict__ boff,
                                                 int* __restrict__ row_start,
                                                 int* __restrict__ cursor, int n, int E) {
  int b = blockIdx.x, tid = threadIdx.x;
  int base = b * 1024 + tid * 4;
  int c[4], s = 0;
#pragma unroll
  for (int k = 0; k < 4; ++k) {
    int i = base + k;
    c[k] = (i < n) ? (int)(pk[i] & 0xffffffffull) : 0;
    s += c[k];
  }
  __shared__ int sm[256];
  sm[tid] = s;
  __syncthreads();
  for (int off = 1; off < 256; off <<= 1) {
    int v = (tid >= off) ? sm[tid - off] : 0;
    __syncthreads();
    sm[tid] += v;
    __syncthreads();
  }
  int run = boff[b] + (tid ? sm[tid - 1] : 0);
#pragma unroll
  for (int k = 0; k < 4; ++k) {
    int i = base + k;
    if (i < n) { row_start[i] = run; cursor[i] = run; run += c[k]; }
  }
  if (b == 0 && tid == 0) row_start[n] = E;
}

__global__ void k_scatter(const int* __restrict__ ei, const float* __restrict__ ew,
                          const float* __restrict__ dinv, int* __restrict__ cursor,
                          int2* __restrict__ csr, int E) {
  int e = blockIdx.x * blockDim.x + threadIdx.x;
  if (e < E) {
    int r = ei[e];
    int c = ei[E + e];
    int pos = atomicAdd(cursor + c, 1);
    float w = ew[e] * dinv[r];                   // dinv[col] applied at end
    csr[pos] = make_int2(r, __float_as_int(w));  // one 8B scattered store
  }
}

// 4 nodes per 256-thread block, one wave each. Lane l owns row halves [4l,4l+4).
template <bool USE16>
__global__ __launch_bounds__(256) void k_main(
    const float* __restrict__ X, const __half* __restrict__ Xh,
    const int* __restrict__ row_start, const int2* __restrict__ csr,
    const float* __restrict__ dinv, const float* __restrict__ Mt,
    const float* __restrict__ cvec, const float* __restrict__ p,
    float* __restrict__ out, int N) {
  int wv = threadIdx.x >> 6;
  int l  = threadIdx.x & 63;
  int node = blockIdx.x * 4 + wv;
  __shared__ float ax[4][256];

  if (node < N) {
    float di = dinv[node];
    float4 acc = make_float4(0.f, 0.f, 0.f, 0.f);
    unsigned loff = (unsigned)l << 3;            // byte offset within row

#define GATH16(EV, WT)                                                     \
    {                                                                      \
      unsigned voff = ((unsigned)(EV) << 9) | loff;                        \
      uint2 q = *(const uint2*)((const char*)Xh + voff);                   \
      __half2 ha = *(__half2*)&q.x;                                        \
      __half2 hb = *(__half2*)&q.y;                                        \
      acc.x = fmaf((WT), __low2float(ha),  acc.x);                         \
      acc.y = fmaf((WT), __high2float(ha), acc.y);                         \
      acc.z = fmaf((WT), __low2float(hb),  acc.z);                         \
      acc.w = fmaf((WT), __high2float(hb), acc.w);                         \
    }

    if (USE16) {
      GATH16(node, di);                          // self loop (weight di)
      int jlo = row_start[node], jhi = row_start[node + 1];
      int j = jlo;
      for (; j + 7 < jhi; j += 8) {
        int2 e0 = csr[j],     e1 = csr[j + 1], e2 = csr[j + 2], e3 = csr[j + 3];
        int2 e4 = csr[j + 4], e5 = csr[j + 5], e6 = csr[j + 6], e7 = csr[j + 7];
        GATH16(e0.x, __int_as_float(e0.y));
        GATH16(e1.x, __int_as_float(e1.y));
        GATH16(e2.x, __int_as_float(e2.y));
        GATH16(e3.x, __int_as_float(e3.y));
        GATH16(e4.x, __int_as_float(e4.y));
        GATH16(e5.x, __int_as_float(e5.y));
        GATH16(e6.x, __int_as_float(e6.y));
        GATH16(e7.x, __int_as_float(e7.y));
      }
      for (; j < jhi; ++j) {
        int2 e0 = csr[j];
        GATH16(e0.x, __int_as_float(e0.y));
      }
    } else {
      const float4* Xv = (const float4*)X;
      float4 a = Xv[(size_t)node * 64 + l];
      acc = make_float4(di * a.x, di * a.y, di * a.z, di * a.w);
      int jlo = row_start[node], jhi = row_start[node + 1];
      for (int j = jlo; j < jhi; ++j) {
        int2 e0 = csr[j];
        float w0 = __int_as_float(e0.y);
        float4 x0 = Xv[(size_t)e0.x * 64 + l];
        acc.x = fmaf(w0, x0.x, acc.x); acc.y = fmaf(w0, x0.y, acc.y);
        acc.z = fmaf(w0, x0.z, acc.z); acc.w = fmaf(w0, x0.w, acc.w);
      }
    }
    acc.x *= di; acc.y *= di; acc.z *= di; acc.w *= di;
    ((float4*)ax[wv])[l] = acc;                  // ax[f*8 + t] row layout
  }
  __syncthreads();
  if (node >= N) return;

  int o = l & 31, g = l >> 5;
  float c = cvec[g * 32 + o];
  float pre[8];
#pragma unroll
  for (int t = 0; t < 8; ++t) pre[t] = c;

  const float*  M   = Mt + g * 1024;
  const float4* axv = (const float4*)ax[wv];
#pragma unroll 8
  for (int f = 0; f < 32; ++f) {
    float  m  = M[f * 32 + o];                   // 128B/half-wave, L1-hot
    float4 a0 = axv[f * 2];                      // LDS broadcast
    float4 a1 = axv[f * 2 + 1];
    pre[0] = fmaf(m, a0.x, pre[0]); pre[1] = fmaf(m, a0.y, pre[1]);
    pre[2] = fmaf(m, a0.z, pre[2]); pre[3] = fmaf(m, a0.w, pre[3]);
    pre[4] = fmaf(m, a1.x, pre[4]); pre[5] = fmaf(m, a1.y, pre[5]);
    pre[6] = fmaf(m, a1.z, pre[6]); pre[7] = fmaf(m, a1.w, pre[7]);
  }

  float v[8];
  if (g == 0) {
#pragma unroll
    for (int t = 0; t < 8; ++t)
      v[t] = __builtin_amdgcn_rcpf(1.f + __expf(pre[t]));     // 1 - sigmoid
  } else {
#pragma unroll
    for (int t = 0; t < 8; ++t)
      v[t] = 1.f - 2.f * __builtin_amdgcn_rcpf(__expf(2.f * pre[t]) + 1.f); // tanh
  }

  float res = 0.f;
#pragma unroll
  for (int t = 0; t < 8; ++t) {
    float other = __shfl(v[t], l ^ 32);          // pair z-half with h-half
    res += p[t] * v[t] * other;
  }
  if (g == 0) out[(size_t)node * 32 + o] = res;
}

extern "C" void kernel_launch(void* const* d_in, const int* in_sizes, int n_in,
                              void* d_out, int out_size, void* d_ws, size_t ws_size,
                              hipStream_t stream) {
  const float* X   = (const float*)d_in[0];
  const int*   ei  = (const int*)d_in[1];    // (2,E) int32 (jax x64 off)
  const float* ew  = (const float*)d_in[2];
  const float* Wz  = (const float*)d_in[3];
  const float* bz  = (const float*)d_in[4];
  const float* Wh  = (const float*)d_in[7];
  const float* bh  = (const float*)d_in[8];
  const float* Lz  = (const float*)d_in[9];
  const float* lzb = (const float*)d_in[10];
  const float* Lh  = (const float*)d_in[13];
  const float* lhb = (const float*)d_in[14];
  const float* att = (const float*)d_in[15];

  int N = in_sizes[0] / 256;   // F_IN * T = 256
  int E = in_sizes[2];

  char* w = (char*)d_ws;
  size_t off = 0;
  auto alloc = [&](size_t bytes) -> void* {
    void* pp = w + off;
    off = (off + bytes + 255) & ~(size_t)255;
    return pp;
  };
  unsigned long long* pk = (unsigned long long*)alloc((size_t)N * 8);
  float* dinv      = (float*)alloc((size_t)N * 4);
  int*   row_start = (int*)  alloc((size_t)(N + 1) * 4);
  int*   cursor    = (int*)  alloc((size_t)N * 4);
  int*   bsum      = (int*)  alloc(256 * 4);
  int*   boff      = (int*)  alloc(256 * 4);
  int2*  csr       = (int2*) alloc((size_t)E * 8);
  float* Mt        = (float*)alloc(2048 * 4);
  float* cvec      = (float*)alloc(64 * 4);
  float* p         = (float*)alloc(8 * 4);
  __half* Xh       = (__half*)(w + off);
  size_t need16    = off + (size_t)N * 256 * 2;
  bool use16 = (ws_size >= need16);
  (void)n_in; (void)out_size;

  long n8   = (long)N * 32;                 // groups of 8 floats
  int  nbe  = (E + 255) / 256;
  int  nbc  = use16 ? (int)((n8 + 255) / 256) : 0;
  int  nb_b = (N + 1023) / 1024;            // <= 256

  hipMemsetAsync(pk, 0, (size_t)N * 8, stream);
  k_fused  <<<2 + nbe + nbc, 256, 0, stream>>>(X, ei, ew, pk, Xh,
                                               Wz, bz, Wh, bh, Lz, lzb, Lh, lhb,
                                               att, Mt, cvec, p, E, n8, nbe);
  k_bsum   <<<nb_b, 256, 0, stream>>>(pk, dinv, bsum, N);
  k_bscan  <<<1, 256, 0, stream>>>(bsum, boff, nb_b);
  k_offsets<<<nb_b, 256, 0, stream>>>(pk, boff, row_start, cursor, N, E);
  k_scatter<<<nbe, 256, 0, stream>>>(ei, ew, dinv, cursor, csr, E);
  if (use16)
    k_main<true><<<(N + 3) / 4, 256, 0, stream>>>(X, Xh, row_start, csr, dinv,
                                                  Mt, cvec, p, (float*)d_out, N);
  else
    k_main<false><<<(N + 3) / 4, 256, 0, stream>>>(X, Xh, row_start, csr, dinv,
                                                   Mt, cvec, p, (float*)d_out, N);
}

// Round 4
// 168.492 us; speedup vs baseline: 1.1528x; 1.1528x over previous
//
#include <hip/hip_runtime.h>
#include <hip/hip_fp16.h>
#include <math.h>

// ---------------------------------------------------------------------------
// A3TGCN2 collapsed (H0 == 0 in every cell):
//   out[n,o] = sum_t p[t] * (1 - sigmoid(pre_z[n,t,o])) * tanh(pre_h[n,t,o])
//   pre_g[n,t,o] = sum_f Agg(X)[n,f,t] * Mg[o,f] + cg[o]
//   Mg = Lg[:, :O] @ Wg (32x32), cg = Lg[:, :O] @ bg + lg_b
//   Agg = sym-normalized adjacency (+self loops) applied ONCE to raw X rows.
// R4: back to 64-thread k_main (wave-uniform node -> scalar csr loads) but
//     keeping fma_mix + 32-bit addressing; k_bscan folded into k_offsets.
// ---------------------------------------------------------------------------

// one u64 atomic per edge: high 32 = weight sum in 2^-24 fixed point, low = count
__global__ __launch_bounds__(256) void k_fused(
    const float* __restrict__ X, const int* __restrict__ ei,
    const float* __restrict__ ew, unsigned long long* __restrict__ pk,
    __half* __restrict__ Xh,
    const float* __restrict__ Wz, const float* __restrict__ bz,
    const float* __restrict__ Wh, const float* __restrict__ bh,
    const float* __restrict__ Lz, const float* __restrict__ lzb,
    const float* __restrict__ Lh, const float* __restrict__ lhb,
    const float* __restrict__ att,
    float* __restrict__ Mt, float* __restrict__ cvec, float* __restrict__ p,
    int E, long n8, int nbe) {
  int b = blockIdx.x;
  int tid = threadIdx.x;
  if (b < 2) {                      // ---- prep (2 blocks) ----
    int g = b;
    const float* L  = g ? Lh  : Lz;
    const float* W  = g ? Wh  : Wz;
    const float* bb = g ? bh  : bz;
    const float* lb = g ? lhb : lzb;
    int o = tid & 31;
    for (int f = tid >> 5; f < 32; f += 8) {
      float s = 0.f;
      for (int k = 0; k < 32; ++k) s += L[o * 64 + k] * W[k * 32 + f];
      Mt[g * 1024 + f * 32 + o] = s;      // transposed [g][f][o]
    }
    if (tid < 32) {
      float c = lb[tid];
      for (int k = 0; k < 32; ++k) c += L[tid * 64 + k] * bb[k];
      cvec[g * 32 + tid] = c;
    }
    if (g == 0 && tid == 0) {
      float m = att[0];
      for (int t = 1; t < 8; ++t) m = fmaxf(m, att[t]);
      float e8[8], sm = 0.f;
      for (int t = 0; t < 8; ++t) { e8[t] = expf(att[t] - m); sm += e8[t]; }
      for (int t = 0; t < 8; ++t) p[t] = e8[t] / sm;
    }
    return;
  }
  b -= 2;
  if (b < nbe) {                    // ---- degree count (atomic-bound) ----
    int e = b * 256 + tid;
    if (e < E) {
      int c = ei[E + e];
      unsigned wfx = (unsigned)(ew[e] * 16777216.0f + 0.5f);
      atomicAdd(pk + c, ((unsigned long long)wfx << 32) | 1ull);
    }
    return;
  }
  b -= nbe;                         // ---- X -> fp16 convert (BW-bound) ----
  long i = (long)b * 256 + tid;
  if (i < n8) {
    const float4* Xv = (const float4*)X;
    float4 a = Xv[2 * i], c = Xv[2 * i + 1];
    union { int4 i4; __half2 h[4]; } u;
    u.h[0] = __floats2half2_rn(a.x, a.y);
    u.h[1] = __floats2half2_rn(a.z, a.w);
    u.h[2] = __floats2half2_rn(c.x, c.y);
    u.h[3] = __floats2half2_rn(c.z, c.w);
    ((int4*)Xh)[i] = u.i4;
  }
}

// per-1024-node block: partial count sums + dinv
__global__ __launch_bounds__(256) void k_bsum(const unsigned long long* __restrict__ pk,
                                              float* __restrict__ dinv,
                                              int* __restrict__ bsum, int n) {
  int b = blockIdx.x, tid = threadIdx.x;
  int base = b * 1024 + tid * 4;
  int s = 0;
#pragma unroll
  for (int k = 0; k < 4; ++k) {
    int i = base + k;
    if (i < n) {
      unsigned long long v = pk[i];
      s += (int)(v & 0xffffffffull);
      float deg = (float)(v >> 32) * (1.0f / 16777216.0f) + 1.0f;  // +1 self
      dinv[i] = rsqrtf(deg);
    }
  }
  __shared__ int sm[256];
  sm[tid] = s;
  __syncthreads();
  for (int off = 128; off > 0; off >>= 1) {
    if (tid < off) sm[tid] += sm[tid + off];
    __syncthreads();
  }
  if (tid == 0) bsum[b] = sm[0];
}

// fused: per-block reduction of bsum[0..b) (replaces k_bscan) + intra-block scan
__global__ __launch_bounds__(256) void k_offsets(const unsigned long long* __restrict__ pk,
                                                 const int* __restrict__ bsum,
                                                 int* __restrict__ row_start,
                                                 int* __restrict__ cursor,
                                                 int n, int E, int nb) {
  int b = blockIdx.x, tid = threadIdx.x;
  __shared__ int sm[256];
  // boff = sum of bsum[0..b)
  sm[tid] = (tid < b) ? bsum[tid] : 0;   // nb <= 256
  __syncthreads();
  for (int off = 128; off > 0; off >>= 1) {
    if (tid < off) sm[tid] += sm[tid + off];
    __syncthreads();
  }
  int boff = sm[0];
  __syncthreads();

  int base = b * 1024 + tid * 4;
  int c[4], s = 0;
#pragma unroll
  for (int k = 0; k < 4; ++k) {
    int i = base + k;
    c[k] = (i < n) ? (int)(pk[i] & 0xffffffffull) : 0;
    s += c[k];
  }
  sm[tid] = s;
  __syncthreads();
  for (int off = 1; off < 256; off <<= 1) {
    int v = (tid >= off) ? sm[tid - off] : 0;
    __syncthreads();
    sm[tid] += v;
    __syncthreads();
  }
  int run = boff + (tid ? sm[tid - 1] : 0);
#pragma unroll
  for (int k = 0; k < 4; ++k) {
    int i = base + k;
    if (i < n) { row_start[i] = run; cursor[i] = run; run += c[k]; }
  }
  if (b == 0 && tid == 0) row_start[n] = E;
}

__global__ void k_scatter(const int* __restrict__ ei, const float* __restrict__ ew,
                          const float* __restrict__ dinv, int* __restrict__ cursor,
                          int2* __restrict__ csr, int E) {
  int e = blockIdx.x * blockDim.x + threadIdx.x;
  if (e < E) {
    int r = ei[e];
    int c = ei[E + e];
    int pos = atomicAdd(cursor + c, 1);
    float w = ew[e] * dinv[r];                   // dinv[col] applied at end
    csr[pos] = make_int2(r, __float_as_int(w));  // one 8B scattered store
  }
}

// One wave per node (node = blockIdx.x stays provably uniform -> scalar csr
// loads). Lane l owns row halves [4l, 4l+4).
template <bool USE16>
__global__ __launch_bounds__(64) void k_main(
    const float* __restrict__ X, const __half* __restrict__ Xh,
    const int* __restrict__ row_start, const int2* __restrict__ csr,
    const float* __restrict__ dinv, const float* __restrict__ Mt,
    const float* __restrict__ cvec, const float* __restrict__ p,
    float* __restrict__ out) {
  int node = blockIdx.x;
  int l = threadIdx.x;
  __shared__ float ax[256];

  float di = dinv[node];
  float4 acc = make_float4(0.f, 0.f, 0.f, 0.f);
  unsigned loff = (unsigned)l << 3;              // byte offset within fp16 row

#define GATH16(EV, WT)                                                     \
  {                                                                        \
    unsigned voff = ((unsigned)(EV) << 9) | loff;                          \
    uint2 q = *(const uint2*)((const char*)Xh + voff);                     \
    __half2 ha = *(__half2*)&q.x;                                          \
    __half2 hb = *(__half2*)&q.y;                                          \
    acc.x = fmaf((WT), __low2float(ha),  acc.x);                           \
    acc.y = fmaf((WT), __high2float(ha), acc.y);                           \
    acc.z = fmaf((WT), __low2float(hb),  acc.z);                           \
    acc.w = fmaf((WT), __high2float(hb), acc.w);                           \
  }

  int jlo = row_start[node], jhi = row_start[node + 1];
  if (USE16) {
    GATH16(node, di);                            // self loop (weight di)
    int j = jlo;
    for (; j + 7 < jhi; j += 8) {
      int2 e0 = csr[j],     e1 = csr[j + 1], e2 = csr[j + 2], e3 = csr[j + 3];
      int2 e4 = csr[j + 4], e5 = csr[j + 5], e6 = csr[j + 6], e7 = csr[j + 7];
      GATH16(e0.x, __int_as_float(e0.y));
      GATH16(e1.x, __int_as_float(e1.y));
      GATH16(e2.x, __int_as_float(e2.y));
      GATH16(e3.x, __int_as_float(e3.y));
      GATH16(e4.x, __int_as_float(e4.y));
      GATH16(e5.x, __int_as_float(e5.y));
      GATH16(e6.x, __int_as_float(e6.y));
      GATH16(e7.x, __int_as_float(e7.y));
    }
    for (; j < jhi; ++j) {
      int2 e0 = csr[j];
      GATH16(e0.x, __int_as_float(e0.y));
    }
  } else {
    const float4* Xv = (const float4*)X;
    float4 a = Xv[(size_t)node * 64 + l];
    acc = make_float4(di * a.x, di * a.y, di * a.z, di * a.w);
    for (int j = jlo; j < jhi; ++j) {
      int2 e0 = csr[j];
      float w0 = __int_as_float(e0.y);
      float4 x0 = Xv[(size_t)e0.x * 64 + l];
      acc.x = fmaf(w0, x0.x, acc.x); acc.y = fmaf(w0, x0.y, acc.y);
      acc.z = fmaf(w0, x0.z, acc.z); acc.w = fmaf(w0, x0.w, acc.w);
    }
  }
  acc.x *= di; acc.y *= di; acc.z *= di; acc.w *= di;

  ((float4*)ax)[l] = acc;                        // ax[f*8 + t] row layout
  __syncthreads();                               // single-wave barrier: free

  int o = l & 31, g = l >> 5;
  float c = cvec[g * 32 + o];
  float pre[8];
#pragma unroll
  for (int t = 0; t < 8; ++t) pre[t] = c;

  const float*  M   = Mt + g * 1024;
  const float4* axv = (const float4*)ax;
#pragma unroll 8
  for (int f = 0; f < 32; ++f) {
    float  m  = M[f * 32 + o];                   // 128B/half-wave, L1-hot
    float4 a0 = axv[f * 2];                      // LDS broadcast
    float4 a1 = axv[f * 2 + 1];
    pre[0] = fmaf(m, a0.x, pre[0]); pre[1] = fmaf(m, a0.y, pre[1]);
    pre[2] = fmaf(m, a0.z, pre[2]); pre[3] = fmaf(m, a0.w, pre[3]);
    pre[4] = fmaf(m, a1.x, pre[4]); pre[5] = fmaf(m, a1.y, pre[5]);
    pre[6] = fmaf(m, a1.z, pre[6]); pre[7] = fmaf(m, a1.w, pre[7]);
  }

  float v[8];
  if (g == 0) {
#pragma unroll
    for (int t = 0; t < 8; ++t)
      v[t] = __builtin_amdgcn_rcpf(1.f + __expf(pre[t]));     // 1 - sigmoid
  } else {
#pragma unroll
    for (int t = 0; t < 8; ++t)
      v[t] = 1.f - 2.f * __builtin_amdgcn_rcpf(__expf(2.f * pre[t]) + 1.f); // tanh
  }

  float res = 0.f;
#pragma unroll
  for (int t = 0; t < 8; ++t) {
    float other = __shfl(v[t], l ^ 32);          // pair z-half with h-half
    res += p[t] * v[t] * other;
  }
  if (g == 0) out[(size_t)node * 32 + o] = res;
}

extern "C" void kernel_launch(void* const* d_in, const int* in_sizes, int n_in,
                              void* d_out, int out_size, void* d_ws, size_t ws_size,
                              hipStream_t stream) {
  const float* X   = (const float*)d_in[0];
  const int*   ei  = (const int*)d_in[1];    // (2,E) int32 (jax x64 off)
  const float* ew  = (const float*)d_in[2];
  const float* Wz  = (const float*)d_in[3];
  const float* bz  = (const float*)d_in[4];
  const float* Wh  = (const float*)d_in[7];
  const float* bh  = (const float*)d_in[8];
  const float* Lz  = (const float*)d_in[9];
  const float* lzb = (const float*)d_in[10];
  const float* Lh  = (const float*)d_in[13];
  const float* lhb = (const float*)d_in[14];
  const float* att = (const float*)d_in[15];

  int N = in_sizes[0] / 256;   // F_IN * T = 256
  int E = in_sizes[2];

  char* w = (char*)d_ws;
  size_t off = 0;
  auto alloc = [&](size_t bytes) -> void* {
    void* pp = w + off;
    off = (off + bytes + 255) & ~(size_t)255;
    return pp;
  };
  unsigned long long* pk = (unsigned long long*)alloc((size_t)N * 8);
  float* dinv      = (float*)alloc((size_t)N * 4);
  int*   row_start = (int*)  alloc((size_t)(N + 1) * 4);
  int*   cursor    = (int*)  alloc((size_t)N * 4);
  int*   bsum      = (int*)  alloc(256 * 4);
  int2*  csr       = (int2*) alloc((size_t)E * 8);
  float* Mt        = (float*)alloc(2048 * 4);
  float* cvec      = (float*)alloc(64 * 4);
  float* p         = (float*)alloc(8 * 4);
  __half* Xh       = (__half*)(w + off);
  size_t need16    = off + (size_t)N * 256 * 2;
  bool use16 = (ws_size >= need16);
  (void)n_in; (void)out_size;

  long n8   = (long)N * 32;                 // groups of 8 floats
  int  nbe  = (E + 255) / 256;
  int  nbc  = use16 ? (int)((n8 + 255) / 256) : 0;
  int  nb_b = (N + 1023) / 1024;            // <= 256

  hipMemsetAsync(pk, 0, (size_t)N * 8, stream);
  k_fused  <<<2 + nbe + nbc, 256, 0, stream>>>(X, ei, ew, pk, Xh,
                                               Wz, bz, Wh, bh, Lz, lzb, Lh, lhb,
                                               att, Mt, cvec, p, E, n8, nbe);
  k_bsum   <<<nb_b, 256, 0, stream>>>(pk, dinv, bsum, N);
  k_offsets<<<nb_b, 256, 0, stream>>>(pk, bsum, row_start, cursor, N, E, nb_b);
  k_scatter<<<nbe, 256, 0, stream>>>(ei, ew, dinv, cursor, csr, E);
  if (use16)
    k_main<true><<<N, 64, 0, stream>>>(X, Xh, row_start, csr, dinv,
                                       Mt, cvec, p, (float*)d_out);
  else
    k_main<false><<<N, 64, 0, stream>>>(X, Xh, row_start, csr, dinv,
                                        Mt, cvec, p, (float*)d_out);
}

// Round 5
// 132.823 us; speedup vs baseline: 1.4624x; 1.2685x over previous
//
#include <hip/hip_runtime.h>
#include <hip/hip_fp16.h>
#include <math.h>

// ---------------------------------------------------------------------------
// A3TGCN2 collapsed (H0 == 0 in every cell):
//   out[n,o] = sum_t p[t] * (1 - sigmoid(pre_z[n,t,o])) * tanh(pre_h[n,t,o])
//   pre_g[n,t,o] = sum_f Agg(X)[n,f,t] * Mg[o,f] + cg[o]
//   Mg = Lg[:, :O] @ Wg (32x32), cg = Lg[:, :O] @ bg + lg_b
//   Agg = sym-normalized adjacency (+self loops) applied ONCE to raw X rows.
// R5: slot-CSR — the packed u64 degree atomic's RETURN VALUE allocates the
//     slot (count|weight-sum|position in one atomic). dinv[src] folded into
//     the fp16 conversion (Xh = dinv*X). Chain: memset -> k1{edges|prep} ->
//     k2 convert -> k3 main. No scan kernels. R4 path kept as ws fallback.
// ---------------------------------------------------------------------------

#define GATH16(EV, WT)                                                     \
  {                                                                        \
    unsigned voff = ((unsigned)(EV) << 9) | loff;                          \
    uint2 q = *(const uint2*)((const char*)Xh + voff);                     \
    __half2 ha = *(__half2*)&q.x;                                          \
    __half2 hb = *(__half2*)&q.y;                                          \
    acc.x = fmaf((WT), __low2float(ha),  acc.x);                           \
    acc.y = fmaf((WT), __high2float(ha), acc.y);                           \
    acc.z = fmaf((WT), __low2float(hb),  acc.z);                           \
    acc.w = fmaf((WT), __high2float(hb), acc.w);                           \
  }

__device__ inline void do_prep(int g, int tid,
    const float* __restrict__ Wz, const float* __restrict__ bz,
    const float* __restrict__ Wh, const float* __restrict__ bh,
    const float* __restrict__ Lz, const float* __restrict__ lzb,
    const float* __restrict__ Lh, const float* __restrict__ lhb,
    const float* __restrict__ att,
    float* __restrict__ Mt, float* __restrict__ cvec, float* __restrict__ p) {
  const float* L  = g ? Lh  : Lz;
  const float* W  = g ? Wh  : Wz;
  const float* bb = g ? bh  : bz;
  const float* lb = g ? lhb : lzb;
  int o = tid & 31;
  for (int f = tid >> 5; f < 32; f += 8) {
    float s = 0.f;
    for (int k = 0; k < 32; ++k) s += L[o * 64 + k] * W[k * 32 + f];
    Mt[g * 1024 + f * 32 + o] = s;      // transposed [g][f][o]
  }
  if (tid < 32) {
    float c = lb[tid];
    for (int k = 0; k < 32; ++k) c += L[tid * 64 + k] * bb[k];
    cvec[g * 32 + tid] = c;
  }
  if (g == 0 && tid == 0) {
    float m = att[0];
    for (int t = 1; t < 8; ++t) m = fmaxf(m, att[t]);
    float e8[8], sm = 0.f;
    for (int t = 0; t < 8; ++t) { e8[t] = expf(att[t] - m); sm += e8[t]; }
    for (int t = 0; t < 8; ++t) p[t] = e8[t] / sm;
  }
}

// ======================= R5 slot path =======================

// edges: ONE u64 atomic gives degree-sum, count, and slot position (old value)
__global__ __launch_bounds__(256) void k1_slot(
    const int* __restrict__ ei, const float* __restrict__ ew,
    unsigned long long* __restrict__ pk, int2* __restrict__ slot, int cap,
    const float* __restrict__ Wz, const float* __restrict__ bz,
    const float* __restrict__ Wh, const float* __restrict__ bh,
    const float* __restrict__ Lz, const float* __restrict__ lzb,
    const float* __restrict__ Lh, const float* __restrict__ lhb,
    const float* __restrict__ att,
    float* __restrict__ Mt, float* __restrict__ cvec, float* __restrict__ p,
    int E) {
  int b = blockIdx.x;
  int tid = threadIdx.x;
  if (b < 2) { do_prep(b, tid, Wz, bz, Wh, bh, Lz, lzb, Lh, lhb, att, Mt, cvec, p); return; }
  int e = (b - 2) * 256 + tid;
  if (e < E) {
    int r = ei[e];
    int c = ei[E + e];
    float w = ew[e];
    unsigned wfx = (unsigned)(w * 16777216.0f + 0.5f);
    unsigned long long old =
        atomicAdd(pk + c, ((unsigned long long)wfx << 32) | 1ull);
    unsigned pos = (unsigned)(old & 0xffffffffull);
    if (pos < (unsigned)cap)
      slot[(size_t)c * cap + pos] = make_int2(r, __float_as_int(w));
  }
}

// X -> fp16, pre-scaled by dinv[node] (recomputed inline from pk)
__global__ __launch_bounds__(256) void k2_conv(
    const float* __restrict__ X, const unsigned long long* __restrict__ pk,
    __half* __restrict__ Xh, long n8) {
  long i = blockIdx.x * (long)blockDim.x + threadIdx.x;
  if (i < n8) {
    int node = (int)(i >> 5);
    unsigned long long v = pk[node];
    float di = rsqrtf((float)(v >> 32) * (1.0f / 16777216.0f) + 1.0f);
    const float4* Xv = (const float4*)X;
    float4 a = Xv[2 * i], c = Xv[2 * i + 1];
    union { int4 i4; __half2 h[4]; } u;
    u.h[0] = __floats2half2_rn(di * a.x, di * a.y);
    u.h[1] = __floats2half2_rn(di * a.z, di * a.w);
    u.h[2] = __floats2half2_rn(di * c.x, di * c.y);
    u.h[3] = __floats2half2_rn(di * c.z, di * c.w);
    ((int4*)Xh)[i] = u.i4;
  }
}

// One wave per node. agg = di * (sum_e ew_e * Xh[src_e] + Xh[node])
__global__ __launch_bounds__(64) void k3_main(
    const __half* __restrict__ Xh, const unsigned long long* __restrict__ pk,
    const int2* __restrict__ slot, int cap,
    const float* __restrict__ Mt, const float* __restrict__ cvec,
    const float* __restrict__ p, float* __restrict__ out) {
  int node = blockIdx.x;
  int l = threadIdx.x;
  __shared__ float ax[256];

  unsigned long long v = pk[node];
  int cnt = (int)(v & 0xffffffffull);
  if (cnt > cap) cnt = cap;
  float di = rsqrtf((float)(v >> 32) * (1.0f / 16777216.0f) + 1.0f);

  float4 acc = make_float4(0.f, 0.f, 0.f, 0.f);
  unsigned loff = (unsigned)l << 3;

  GATH16(node, 1.0f);                            // self (Xh already has dinv)
  const int2* row = slot + (size_t)node * cap;
  int j = 0;
  for (; j + 7 < cnt; j += 8) {
    int2 e0 = row[j],     e1 = row[j + 1], e2 = row[j + 2], e3 = row[j + 3];
    int2 e4 = row[j + 4], e5 = row[j + 5], e6 = row[j + 6], e7 = row[j + 7];
    GATH16(e0.x, __int_as_float(e0.y));
    GATH16(e1.x, __int_as_float(e1.y));
    GATH16(e2.x, __int_as_float(e2.y));
    GATH16(e3.x, __int_as_float(e3.y));
    GATH16(e4.x, __int_as_float(e4.y));
    GATH16(e5.x, __int_as_float(e5.y));
    GATH16(e6.x, __int_as_float(e6.y));
    GATH16(e7.x, __int_as_float(e7.y));
  }
  for (; j < cnt; ++j) {
    int2 e0 = row[j];
    GATH16(e0.x, __int_as_float(e0.y));
  }
  acc.x *= di; acc.y *= di; acc.z *= di; acc.w *= di;

  ((float4*)ax)[l] = acc;                        // ax[f*8 + t] row layout
  __syncthreads();                               // single-wave: free

  int o = l & 31, g = l >> 5;
  float c = cvec[g * 32 + o];
  float pre[8];
#pragma unroll
  for (int t = 0; t < 8; ++t) pre[t] = c;

  const float*  M   = Mt + g * 1024;
  const float4* axv = (const float4*)ax;
#pragma unroll 8
  for (int f = 0; f < 32; ++f) {
    float  m  = M[f * 32 + o];
    float4 a0 = axv[f * 2];
    float4 a1 = axv[f * 2 + 1];
    pre[0] = fmaf(m, a0.x, pre[0]); pre[1] = fmaf(m, a0.y, pre[1]);
    pre[2] = fmaf(m, a0.z, pre[2]); pre[3] = fmaf(m, a0.w, pre[3]);
    pre[4] = fmaf(m, a1.x, pre[4]); pre[5] = fmaf(m, a1.y, pre[5]);
    pre[6] = fmaf(m, a1.z, pre[6]); pre[7] = fmaf(m, a1.w, pre[7]);
  }

  float vv[8];
  if (g == 0) {
#pragma unroll
    for (int t = 0; t < 8; ++t)
      vv[t] = __builtin_amdgcn_rcpf(1.f + __expf(pre[t]));     // 1 - sigmoid
  } else {
#pragma unroll
    for (int t = 0; t < 8; ++t)
      vv[t] = 1.f - 2.f * __builtin_amdgcn_rcpf(__expf(2.f * pre[t]) + 1.f);
  }

  float res = 0.f;
#pragma unroll
  for (int t = 0; t < 8; ++t) {
    float other = __shfl(vv[t], l ^ 32);
    res += p[t] * vv[t] * other;
  }
  if (g == 0) out[(size_t)node * 32 + o] = res;
}

// ======================= R4 fallback path =======================

__global__ __launch_bounds__(256) void k_fused(
    const float* __restrict__ X, const int* __restrict__ ei,
    const float* __restrict__ ew, unsigned long long* __restrict__ pk,
    __half* __restrict__ Xh,
    const float* __restrict__ Wz, const float* __restrict__ bz,
    const float* __restrict__ Wh, const float* __restrict__ bh,
    const float* __restrict__ Lz, const float* __restrict__ lzb,
    const float* __restrict__ Lh, const float* __restrict__ lhb,
    const float* __restrict__ att,
    float* __restrict__ Mt, float* __restrict__ cvec, float* __restrict__ p,
    int E, long n8, int nbe) {
  int b = blockIdx.x;
  int tid = threadIdx.x;
  if (b < 2) { do_prep(b, tid, Wz, bz, Wh, bh, Lz, lzb, Lh, lhb, att, Mt, cvec, p); return; }
  b -= 2;
  if (b < nbe) {
    int e = b * 256 + tid;
    if (e < E) {
      int c = ei[E + e];
      unsigned wfx = (unsigned)(ew[e] * 16777216.0f + 0.5f);
      atomicAdd(pk + c, ((unsigned long long)wfx << 32) | 1ull);
    }
    return;
  }
  b -= nbe;
  long i = (long)b * 256 + tid;
  if (i < n8) {
    const float4* Xv = (const float4*)X;
    float4 a = Xv[2 * i], c = Xv[2 * i + 1];
    union { int4 i4; __half2 h[4]; } u;
    u.h[0] = __floats2half2_rn(a.x, a.y);
    u.h[1] = __floats2half2_rn(a.z, a.w);
    u.h[2] = __floats2half2_rn(c.x, c.y);
    u.h[3] = __floats2half2_rn(c.z, c.w);
    ((int4*)Xh)[i] = u.i4;
  }
}

__global__ __launch_bounds__(256) void k_bsum(const unsigned long long* __restrict__ pk,
                                              float* __restrict__ dinv,
                                              int* __restrict__ bsum, int n) {
  int b = blockIdx.x, tid = threadIdx.x;
  int base = b * 1024 + tid * 4;
  int s = 0;
#pragma unroll
  for (int k = 0; k < 4; ++k) {
    int i = base + k;
    if (i < n) {
      unsigned long long v = pk[i];
      s += (int)(v & 0xffffffffull);
      float deg = (float)(v >> 32) * (1.0f / 16777216.0f) + 1.0f;
      dinv[i] = rsqrtf(deg);
    }
  }
  __shared__ int sm[256];
  sm[tid] = s;
  __syncthreads();
  for (int off = 128; off > 0; off >>= 1) {
    if (tid < off) sm[tid] += sm[tid + off];
    __syncthreads();
  }
  if (tid == 0) bsum[b] = sm[0];
}

__global__ __launch_bounds__(256) void k_offsets(const unsigned long long* __restrict__ pk,
                                                 const int* __restrict__ bsum,
                                                 int* __restrict__ row_start,
                                                 int* __restrict__ cursor,
                                                 int n, int E, int nb) {
  int b = blockIdx.x, tid = threadIdx.x;
  __shared__ int sm[256];
  sm[tid] = (tid < b) ? bsum[tid] : 0;
  __syncthreads();
  for (int off = 128; off > 0; off >>= 1) {
    if (tid < off) sm[tid] += sm[tid + off];
    __syncthreads();
  }
  int boff = sm[0];
  __syncthreads();

  int base = b * 1024 + tid * 4;
  int c[4], s = 0;
#pragma unroll
  for (int k = 0; k < 4; ++k) {
    int i = base + k;
    c[k] = (i < n) ? (int)(pk[i] & 0xffffffffull) : 0;
    s += c[k];
  }
  sm[tid] = s;
  __syncthreads();
  for (int off = 1; off < 256; off <<= 1) {
    int v = (tid >= off) ? sm[tid - off] : 0;
    __syncthreads();
    sm[tid] += v;
    __syncthreads();
  }
  int run = boff + (tid ? sm[tid - 1] : 0);
#pragma unroll
  for (int k = 0; k < 4; ++k) {
    int i = base + k;
    if (i < n) { row_start[i] = run; cursor[i] = run; run += c[k]; }
  }
  if (b == 0 && tid == 0) row_start[n] = E;
}

__global__ void k_scatter(const int* __restrict__ ei, const float* __restrict__ ew,
                          const float* __restrict__ dinv, int* __restrict__ cursor,
                          int2* __restrict__ csr, int E) {
  int e = blockIdx.x * blockDim.x + threadIdx.x;
  if (e < E) {
    int r = ei[e];
    int c = ei[E + e];
    int pos = atomicAdd(cursor + c, 1);
    float w = ew[e] * dinv[r];
    csr[pos] = make_int2(r, __float_as_int(w));
  }
}

template <bool USE16>
__global__ __launch_bounds__(64) void k_main(
    const float* __restrict__ X, const __half* __restrict__ Xh,
    const int* __restrict__ row_start, const int2* __restrict__ csr,
    const float* __restrict__ dinv, const float* __restrict__ Mt,
    const float* __restrict__ cvec, const float* __restrict__ p,
    float* __restrict__ out) {
  int node = blockIdx.x;
  int l = threadIdx.x;
  __shared__ float ax[256];

  float di = dinv[node];
  float4 acc = make_float4(0.f, 0.f, 0.f, 0.f);
  unsigned loff = (unsigned)l << 3;

  int jlo = row_start[node], jhi = row_start[node + 1];
  if (USE16) {
    GATH16(node, di);
    int j = jlo;
    for (; j + 7 < jhi; j += 8) {
      int2 e0 = csr[j],     e1 = csr[j + 1], e2 = csr[j + 2], e3 = csr[j + 3];
      int2 e4 = csr[j + 4], e5 = csr[j + 5], e6 = csr[j + 6], e7 = csr[j + 7];
      GATH16(e0.x, __int_as_float(e0.y));
      GATH16(e1.x, __int_as_float(e1.y));
      GATH16(e2.x, __int_as_float(e2.y));
      GATH16(e3.x, __int_as_float(e3.y));
      GATH16(e4.x, __int_as_float(e4.y));
      GATH16(e5.x, __int_as_float(e5.y));
      GATH16(e6.x, __int_as_float(e6.y));
      GATH16(e7.x, __int_as_float(e7.y));
    }
    for (; j < jhi; ++j) {
      int2 e0 = csr[j];
      GATH16(e0.x, __int_as_float(e0.y));
    }
  } else {
    const float4* Xv = (const float4*)X;
    float4 a = Xv[(size_t)node * 64 + l];
    acc = make_float4(di * a.x, di * a.y, di * a.z, di * a.w);
    for (int j = jlo; j < jhi; ++j) {
      int2 e0 = csr[j];
      float w0 = __int_as_float(e0.y);
      float4 x0 = Xv[(size_t)e0.x * 64 + l];
      acc.x = fmaf(w0, x0.x, acc.x); acc.y = fmaf(w0, x0.y, acc.y);
      acc.z = fmaf(w0, x0.z, acc.z); acc.w = fmaf(w0, x0.w, acc.w);
    }
  }
  acc.x *= di; acc.y *= di; acc.z *= di; acc.w *= di;

  ((float4*)ax)[l] = acc;
  __syncthreads();

  int o = l & 31, g = l >> 5;
  float c = cvec[g * 32 + o];
  float pre[8];
#pragma unroll
  for (int t = 0; t < 8; ++t) pre[t] = c;

  const float*  M   = Mt + g * 1024;
  const float4* axv = (const float4*)ax;
#pragma unroll 8
  for (int f = 0; f < 32; ++f) {
    float  m  = M[f * 32 + o];
    float4 a0 = axv[f * 2];
    float4 a1 = axv[f * 2 + 1];
    pre[0] = fmaf(m, a0.x, pre[0]); pre[1] = fmaf(m, a0.y, pre[1]);
    pre[2] = fmaf(m, a0.z, pre[2]); pre[3] = fmaf(m, a0.w, pre[3]);
    pre[4] = fmaf(m, a1.x, pre[4]); pre[5] = fmaf(m, a1.y, pre[5]);
    pre[6] = fmaf(m, a1.z, pre[6]); pre[7] = fmaf(m, a1.w, pre[7]);
  }

  float vv[8];
  if (g == 0) {
#pragma unroll
    for (int t = 0; t < 8; ++t)
      vv[t] = __builtin_amdgcn_rcpf(1.f + __expf(pre[t]));
  } else {
#pragma unroll
    for (int t = 0; t < 8; ++t)
      vv[t] = 1.f - 2.f * __builtin_amdgcn_rcpf(__expf(2.f * pre[t]) + 1.f);
  }

  float res = 0.f;
#pragma unroll
  for (int t = 0; t < 8; ++t) {
    float other = __shfl(vv[t], l ^ 32);
    res += p[t] * vv[t] * other;
  }
  if (g == 0) out[(size_t)node * 32 + o] = res;
}

// ======================= launcher =======================

extern "C" void kernel_launch(void* const* d_in, const int* in_sizes, int n_in,
                              void* d_out, int out_size, void* d_ws, size_t ws_size,
                              hipStream_t stream) {
  const float* X   = (const float*)d_in[0];
  const int*   ei  = (const int*)d_in[1];    // (2,E) int32 (jax x64 off)
  const float* ew  = (const float*)d_in[2];
  const float* Wz  = (const float*)d_in[3];
  const float* bz  = (const float*)d_in[4];
  const float* Wh  = (const float*)d_in[7];
  const float* bh  = (const float*)d_in[8];
  const float* Lz  = (const float*)d_in[9];
  const float* lzb = (const float*)d_in[10];
  const float* Lh  = (const float*)d_in[13];
  const float* lhb = (const float*)d_in[14];
  const float* att = (const float*)d_in[15];

  int N = in_sizes[0] / 256;   // F_IN * T = 256
  int E = in_sizes[2];
  (void)n_in; (void)out_size;

  long n8  = (long)N * 32;
  int  nbe = (E + 255) / 256;

  // ---- slot path sizing: pk | Mt | cvec | p | Xh | slot(N*cap*8) ----
  {
    size_t off = 0;
    auto al = [&](size_t b) { size_t q = off; off = (off + b + 255) & ~(size_t)255; return q; };
    size_t o_pk  = al((size_t)N * 8);
    size_t o_mt  = al(2048 * 4);
    size_t o_cv  = al(64 * 4);
    size_t o_p   = al(8 * 4);
    size_t o_xh  = al((size_t)N * 256 * 2);
    size_t fixed = off;
    int cap = 0;
    for (int c : {64, 48, 32}) {
      if (fixed + (size_t)N * c * 8 <= ws_size) { cap = c; break; }
    }
    if (cap) {
      char* w = (char*)d_ws;
      unsigned long long* pk = (unsigned long long*)(w + o_pk);
      float* Mt   = (float*)(w + o_mt);
      float* cvec = (float*)(w + o_cv);
      float* p    = (float*)(w + o_p);
      __half* Xh  = (__half*)(w + o_xh);
      int2*  slot = (int2*)(w + fixed);

      hipMemsetAsync(pk, 0, (size_t)N * 8, stream);
      k1_slot<<<2 + nbe, 256, 0, stream>>>(ei, ew, pk, slot, cap,
                                           Wz, bz, Wh, bh, Lz, lzb, Lh, lhb,
                                           att, Mt, cvec, p, E);
      k2_conv<<<(int)((n8 + 255) / 256), 256, 0, stream>>>(X, pk, Xh, n8);
      k3_main<<<N, 64, 0, stream>>>(Xh, pk, slot, cap, Mt, cvec, p,
                                    (float*)d_out);
      return;
    }
  }

  // ---- R4 fallback ----
  char* w = (char*)d_ws;
  size_t off = 0;
  auto alloc = [&](size_t bytes) -> void* {
    void* pp = w + off;
    off = (off + bytes + 255) & ~(size_t)255;
    return pp;
  };
  unsigned long long* pk = (unsigned long long*)alloc((size_t)N * 8);
  float* dinv      = (float*)alloc((size_t)N * 4);
  int*   row_start = (int*)  alloc((size_t)(N + 1) * 4);
  int*   cursor    = (int*)  alloc((size_t)N * 4);
  int*   bsum      = (int*)  alloc(256 * 4);
  int2*  csr       = (int2*) alloc((size_t)E * 8);
  float* Mt        = (float*)alloc(2048 * 4);
  float* cvec      = (float*)alloc(64 * 4);
  float* p         = (float*)alloc(8 * 4);
  __half* Xh       = (__half*)(w + off);
  size_t need16    = off + (size_t)N * 256 * 2;
  bool use16 = (ws_size >= need16);

  int nbc  = use16 ? (int)((n8 + 255) / 256) : 0;
  int nb_b = (N + 1023) / 1024;

  hipMemsetAsync(pk, 0, (size_t)N * 8, stream);
  k_fused  <<<2 + nbe + nbc, 256, 0, stream>>>(X, ei, ew, pk, Xh,
                                               Wz, bz, Wh, bh, Lz, lzb, Lh, lhb,
                                               att, Mt, cvec, p, E, n8, nbe);
  k_bsum   <<<nb_b, 256, 0, stream>>>(pk, dinv, bsum, N);
  k_offsets<<<nb_b, 256, 0, stream>>>(pk, bsum, row_start, cursor, N, E, nb_b);
  k_scatter<<<nbe, 256, 0, stream>>>(ei, ew, dinv, cursor, csr, E);
  if (use16)
    k_main<true><<<N, 64, 0, stream>>>(X, Xh, row_start, csr, dinv,
                                       Mt, cvec, p, (float*)d_out);
  else
    k_main<false><<<N, 64, 0, stream>>>(X, Xh, row_start, csr, dinv,
                                        Mt, cvec, p, (float*)d_out);
}